// Round 1
// baseline (1259.007 us; speedup 1.0000x reference)
//
#include <hip/hip_runtime.h>
#include <math.h>

// Problem constants
#define B_    32
#define L_    4096
#define CIN_  128
#define H_    256
#define T_    4094          // L - K + 1
#define KTOT_ 384           // CIN * K

// Tiling
#define TC_   64            // timesteps per chunk
#define NC_   64            // chunks (64*64 = 4096 >= 4094)
#define HT_   64            // h-channels per block -> 192 conv channels (z,f,o)
#define KT_   32            // K-tile
#define NKT_  12            // 384/32

// LDS pitches (floats)
#define XP_   132           // x-slice row pitch (16B-aligned, odd-ish banking)
#define WP_   196           // W-tile row pitch

// ---------------------------------------------------------------------------
// Kernel 0: pack W (c, i, k) -> Wt[c][kk], kk = k*128 + i  (contiguous per c)
// ---------------------------------------------------------------------------
__global__ __launch_bounds__(256) void packW_kernel(const float* __restrict__ W,
                                                    float* __restrict__ Wt) {
  int idx = blockIdx.x * 256 + threadIdx.x;
  if (idx < 768 * KTOT_) {
    int c = idx / KTOT_;
    int kk = idx - c * KTOT_;
    int i = kk & 127, k = kk >> 7;
    Wt[idx] = W[(size_t)c * KTOT_ + i * 3 + k];
  }
}

// ---------------------------------------------------------------------------
// Kernel 1: fused conv(GEMM) + activations + chunked fo-pool scan
// grid: (4 h-tiles, 64 chunks, 32 batch)  block: 256
// ---------------------------------------------------------------------------
__global__ __launch_bounds__(256) void conv_scan_kernel(
    const float* __restrict__ x, const float* __restrict__ Wt,
    const float* __restrict__ bias, float* __restrict__ Pws,
    float* __restrict__ Sws) {
  __shared__ float xs[66 * XP_];      // 34848 B: x rows t0..t0+65
  __shared__ float wsh[KT_ * WP_];    // 25088 B: W K-tile [kk][c]; reused as gates

  const int tid = threadIdx.x;
  const int tx = tid & 15;            // -> 12 channels [tx*12, tx*12+12)
  const int ty = tid >> 4;            // -> 4 timesteps m = mi*16 + ty
  const int h0 = blockIdx.x * HT_;
  const int chunk = blockIdx.y;
  const int bb = blockIdx.z;
  const int t0 = chunk * TC_;

  // ---- stage x slice (rows t0..t0+65, clamped) ----
  for (int v = tid; v < 66 * 32; v += 256) {
    int row = v >> 5;
    int col = (v & 31) << 2;
    int r = t0 + row;
    if (r > L_ - 1) r = L_ - 1;       // clamped rows feed only invalid t, skipped in scan
    const float4 xv = *(const float4*)&x[((size_t)bb * L_ + r) * CIN_ + col];
    *(float4*)&xs[row * XP_ + col] = xv;
  }

  float acc[4][12];
#pragma unroll
  for (int mi = 0; mi < 4; ++mi)
#pragma unroll
    for (int j = 0; j < 12; ++j) acc[mi][j] = 0.f;

  // ---- GEMM: M=64 x N=192 x K=384 ----
  for (int kt = 0; kt < NKT_; ++kt) {
    __syncthreads();
    // stage W tile: KT_ x 192 (transpose scatter; reads are contiguous float4)
    for (int v = tid; v < 192 * (KT_ / 4); v += 256) {  // 1536 float4
      int c = v >> 3;
      int klv = v & 7;
      int g = c >> 6, hl = c & 63;
      const float4 w = *(const float4*)&Wt[(size_t)((g << 8) + h0 + hl) * KTOT_ + kt * KT_ + klv * 4];
      wsh[(klv * 4 + 0) * WP_ + c] = w.x;
      wsh[(klv * 4 + 1) * WP_ + c] = w.y;
      wsh[(klv * 4 + 2) * WP_ + c] = w.z;
      wsh[(klv * 4 + 3) * WP_ + c] = w.w;
    }
    __syncthreads();
#pragma unroll
    for (int kk4 = 0; kk4 < KT_; kk4 += 4) {
      const int kkg = kt * KT_ + kk4;
      const int k = kkg >> 7, i0 = kkg & 127;   // constant within aligned 4-group
      float4 a4[4];
#pragma unroll
      for (int mi = 0; mi < 4; ++mi)
        a4[mi] = *(const float4*)&xs[(mi * 16 + ty + k) * XP_ + i0];
#pragma unroll
      for (int q = 0; q < 4; ++q) {
        const float4 b0 = *(const float4*)&wsh[(kk4 + q) * WP_ + tx * 12];
        const float4 b1 = *(const float4*)&wsh[(kk4 + q) * WP_ + tx * 12 + 4];
        const float4 b2 = *(const float4*)&wsh[(kk4 + q) * WP_ + tx * 12 + 8];
#pragma unroll
        for (int mi = 0; mi < 4; ++mi) {
          const float av = (q == 0) ? a4[mi].x : (q == 1) ? a4[mi].y
                         : (q == 2) ? a4[mi].z : a4[mi].w;
          acc[mi][0] += av * b0.x;  acc[mi][1] += av * b0.y;
          acc[mi][2] += av * b0.z;  acc[mi][3] += av * b0.w;
          acc[mi][4] += av * b1.x;  acc[mi][5] += av * b1.y;
          acc[mi][6] += av * b1.z;  acc[mi][7] += av * b1.w;
          acc[mi][8] += av * b2.x;  acc[mi][9] += av * b2.y;
          acc[mi][10] += av * b2.z; acc[mi][11] += av * b2.w;
        }
      }
    }
  }

  // ---- fo-pool scan: h_t = (O*F) h + O*(1-F)*Z; chunk-affine (P, S) ----
  float P = 1.f, S = 0.f;
  float bz = 0.f, bfv = 0.f, bo = 0.f;
  if (tid < 64) {
    bz  = bias[h0 + tid];
    bfv = bias[256 + h0 + tid];
    bo  = bias[512 + h0 + tid];
  }
#pragma unroll
  for (int s = 0; s < 4; ++s) {       // fully unrolled: acc[s] stays in registers
    __syncthreads();                  // protects previous stage's reads / last W tile
    {
      float4 g0 = make_float4(acc[s][0], acc[s][1], acc[s][2], acc[s][3]);
      float4 g1 = make_float4(acc[s][4], acc[s][5], acc[s][6], acc[s][7]);
      float4 g2 = make_float4(acc[s][8], acc[s][9], acc[s][10], acc[s][11]);
      *(float4*)&wsh[ty * 192 + tx * 12]     = g0;   // row ty holds m = s*16+ty
      *(float4*)&wsh[ty * 192 + tx * 12 + 4] = g1;
      *(float4*)&wsh[ty * 192 + tx * 12 + 8] = g2;
    }
    __syncthreads();
    if (tid < 64) {
      for (int mt = 0; mt < 16; ++mt) {
        const int t = t0 + s * 16 + mt;
        if (t < T_) {
          const float zr  = wsh[mt * 192 + tid] + bz;
          const float fr  = wsh[mt * 192 + 64 + tid] + bfv;
          const float orr = wsh[mt * 192 + 128 + tid] + bo;
          const float zt = tanhf(zr);
          const float ft = 1.f / (1.f + __expf(-fr));
          const float ot = 1.f / (1.f + __expf(-orr));
          const float A  = ot * ft;
          const float Bv = ot * (1.f - ft) * zt;
          S = A * S + Bv;
          P = A * P;
        }
      }
    }
  }
  if (tid < 64) {
    const size_t o = ((size_t)bb * NC_ + chunk) * H_ + h0 + tid;
    Pws[o] = P;
    Sws[o] = S;
  }
}

// ---------------------------------------------------------------------------
// Kernel 2: compose the 64 chunk-affine maps per (b, h) -> final h_T
// ---------------------------------------------------------------------------
__global__ __launch_bounds__(256) void combine_kernel(const float* __restrict__ Pws,
                                                      const float* __restrict__ Sws,
                                                      float* __restrict__ out) {
  const int idx = blockIdx.x * 256 + threadIdx.x;  // 8192 = B*H
  const int b = idx >> 8;
  const int hh = idx & 255;
  float h = 0.f;
  for (int c = 0; c < NC_; ++c) {
    const float p = Pws[((size_t)b * NC_ + c) * H_ + hh];
    const float s = Sws[((size_t)b * NC_ + c) * H_ + hh];
    h = p * h + s;
  }
  out[idx] = h;
}

// ---------------------------------------------------------------------------
extern "C" void kernel_launch(void* const* d_in, const int* in_sizes, int n_in,
                              void* d_out, int out_size, void* d_ws, size_t ws_size,
                              hipStream_t stream) {
  const float* x    = (const float*)d_in[0];
  const float* W    = (const float*)d_in[1];
  const float* bias = (const float*)d_in[2];
  float* out = (float*)d_out;

  float* Wt  = (float*)d_ws;                  // 768*384 floats = 1.18 MB
  float* Pws = Wt + 768 * KTOT_;              // 32*64*256 floats = 2 MB
  float* Sws = Pws + B_ * NC_ * H_;           // 2 MB

  packW_kernel<<<1152, 256, 0, stream>>>(W, Wt);
  conv_scan_kernel<<<dim3(4, NC_, B_), 256, 0, stream>>>(x, Wt, bias, Pws, Sws);
  combine_kernel<<<32, 256, 0, stream>>>(Pws, Sws, out);
}

// Round 2
// 328.563 us; speedup vs baseline: 3.8319x; 3.8319x over previous
//
#include <hip/hip_runtime.h>
#include <math.h>

// Problem constants
#define B_    32
#define L_    4096
#define CIN_  128
#define H_    256
#define T_    4094          // L - K + 1
#define KTOT_ 384           // CIN * K

#define TC_   64            // timesteps per chunk (M tile)
#define NC_   64            // chunks
#define NG_   192           // channels per block (z,f,o x 64 h)
#define NKT_  12            // K-steps of 32

typedef float f32x4 __attribute__((ext_vector_type(4)));
typedef short s16x8 __attribute__((ext_vector_type(8)));

typedef __attribute__((address_space(3))) void lds_void;
typedef const __attribute__((address_space(1))) void gbl_void;

static __device__ __forceinline__ unsigned short f2bf(float f) {
  unsigned u = __builtin_bit_cast(unsigned, f);
  u = (u + 0x7FFFu + ((u >> 16) & 1u)) >> 16;
  return (unsigned short)u;
}

// ---------------------------------------------------------------------------
// Kernel 0: pack W (oc, i, k) fp32 -> bf16 tiles [g][kt][kgrp][c192][kk8]
// so that a linear global_load_lds stage yields conflict-free MFMA B-frag reads.
// c = gate*64 + h_lo  maps to  oc = gate*256 + g*64 + h_lo.
// kk = kt*32 + kgrp*8 + e ; k = kk>>7 ; i = kk&127.
// ---------------------------------------------------------------------------
__global__ __launch_bounds__(256) void packW_bf16(const float* __restrict__ W,
                                                  unsigned short* __restrict__ Wb) {
  const int idx = blockIdx.x * 256 + threadIdx.x;     // exactly 294912 = 1152*256
  const int e = idx & 7;
  int t = idx >> 3;
  const int c = t % NG_;
  t /= NG_;
  const int kgrp = t & 3;
  t >>= 2;
  const int kt = t % NKT_;
  const int g = t / NKT_;
  const int kk = kt * 32 + kgrp * 8 + e;
  const int i = kk & 127, k = kk >> 7;
  const int gate = c >> 6, hl = c & 63;
  const int oc = gate * 256 + g * 64 + hl;
  Wb[idx] = f2bf(W[(size_t)oc * KTOT_ + i * 3 + k]);
}

// ---------------------------------------------------------------------------
// Kernel 1: fused bf16-MFMA conv + activations + chunked fo-pool scan
// grid (4 h-groups, 64 chunks, 32 batch), block 256 (4 waves)
// ---------------------------------------------------------------------------
__global__ __launch_bounds__(256, 3) void conv_scan_mfma(
    const float* __restrict__ x, const unsigned short* __restrict__ Wb,
    const float* __restrict__ bias, float* __restrict__ Pws,
    float* __restrict__ Sws) {
  // LDS: xs = 66 rows x 128 bf16 (256B pitch, XOR-swizzled)  = 16896 B
  //      B double-buffer: 2 x 12288 B (half reused as f32 gates buffer)
  __shared__ __align__(16) char smem[16896 + 2 * 12288];
  char* xs = smem;
  char* bsh = smem + 16896;

  const int tid = threadIdx.x;
  const int w = tid >> 6;          // wave 0..3 -> owns channels [48w,48w+48)
  const int l = tid & 63;
  const int lr = l & 15;           // fragment row / col-within-16
  const int lg = l >> 4;           // fragment k-group
  const int g = blockIdx.x;
  const int chunk = blockIdx.y;
  const int bb = blockIdx.z;
  const int t0 = chunk * TC_;

  const unsigned short* wsrc = Wb + (size_t)g * (NKT_ * 6144);

  // ---- prologue: issue B tile kt=0 into half 0 (3 x 16B per thread) ----
#pragma unroll
  for (int it = 0; it < 3; ++it) {
    __builtin_amdgcn_global_load_lds(
        (gbl_void*)(wsrc + (size_t)(it * 256 + tid) * 8),
        (lds_void*)(bsh + it * 4096 + w * 1024), 16, 0, 0);
  }

  // ---- stage x slice fp32 -> bf16 into swizzled xs ----
  for (int v = tid; v < 66 * 32; v += 256) {
    const int row = v >> 5;
    const int colb = (v & 31) * 8;                 // byte offset of 4 bf16
    int r = t0 + row;
    if (r > L_ - 1) r = L_ - 1;                    // clamp; only feeds t>=T_, discarded
    const float4 xv = *(const float4*)&x[((size_t)bb * L_ + r) * CIN_ + (v & 31) * 4];
    unsigned short u0 = f2bf(xv.x), u1 = f2bf(xv.y), u2 = f2bf(xv.z), u3 = f2bf(xv.w);
    unsigned long long pk = (unsigned long long)u0 | ((unsigned long long)u1 << 16) |
                            ((unsigned long long)u2 << 32) | ((unsigned long long)u3 << 48);
    *(unsigned long long*)(xs + row * 256 + (colb ^ ((row & 7) << 4))) = pk;
  }

  // ---- GEMM: M=64 x N=192 x K=384, 12 K-steps, 2-phase pipeline ----
  f32x4 acc[4][3];
#pragma unroll
  for (int mi = 0; mi < 4; ++mi)
#pragma unroll
    for (int nj = 0; nj < 3; ++nj) acc[mi][nj] = (f32x4)0.f;

  for (int kt = 0; kt < NKT_; ++kt) {
    __syncthreads();                               // B[kt] + xs ready (vm/lgkm drained)
    if (kt < NKT_ - 1) {                           // issue next tile into other half
      const unsigned short* src = wsrc + (size_t)(kt + 1) * 6144;
      char* dst = bsh + ((kt + 1) & 1) * 12288;
#pragma unroll
      for (int it = 0; it < 3; ++it) {
        __builtin_amdgcn_global_load_lds(
            (gbl_void*)(src + (size_t)(it * 256 + tid) * 8),
            (lds_void*)(dst + it * 4096 + w * 1024), 16, 0, 0);
      }
    }
    const int kof = kt >> 2;                       // which of 3 taps
    const int cb = (kt & 3) * 64 + lg * 16;        // byte col in xs row
    s16x8 a[4], b[3];
#pragma unroll
    for (int mi = 0; mi < 4; ++mi) {
      const int row = mi * 16 + lr + kof;
      a[mi] = *(const s16x8*)(xs + row * 256 + (cb ^ ((row & 7) << 4)));
    }
    const char* bh = bsh + (kt & 1) * 12288;
#pragma unroll
    for (int nj = 0; nj < 3; ++nj)
      b[nj] = *(const s16x8*)(bh + (lg * NG_ + w * 48 + nj * 16 + lr) * 16);
#pragma unroll
    for (int mi = 0; mi < 4; ++mi)
#pragma unroll
      for (int nj = 0; nj < 3; ++nj)
        acc[mi][nj] = __builtin_amdgcn_mfma_f32_16x16x32_bf16(a[mi], b[nj], acc[mi][nj], 0, 0, 0);
  }

  // ---- fused fo-pool scan over 4 stages of 16 timesteps ----
  float P = 1.f, S = 0.f;
  float bz = 0.f, bfv = 0.f, bo = 0.f;
  if (tid < 64) {
    bz = bias[g * 64 + tid];
    bfv = bias[256 + g * 64 + tid];
    bo = bias[512 + g * 64 + tid];
  }
  float* gsh = (float*)bsh;                        // 16 x 192 f32 = 12288 B (half 0)
#pragma unroll
  for (int s = 0; s < 4; ++s) {
    __syncthreads();                               // prev reads done / GEMM reads done
#pragma unroll
    for (int nj = 0; nj < 3; ++nj) {
#pragma unroll
      for (int r = 0; r < 4; ++r) {
        const int m = lg * 4 + r;                  // C frag: col=l&15, row=(l>>4)*4+r
        const int c = w * 48 + nj * 16 + lr;
        gsh[m * NG_ + c] = acc[s][nj][r];
      }
    }
    __syncthreads();
    if (tid < 64) {
#pragma unroll
      for (int mt = 0; mt < 16; ++mt) {
        const int t = t0 + s * 16 + mt;
        if (t < T_) {
          const float zr = gsh[mt * NG_ + tid] + bz;
          const float fr = gsh[mt * NG_ + 64 + tid] + bfv;
          const float orr = gsh[mt * NG_ + 128 + tid] + bo;
          const float zt = tanhf(zr);
          const float ft = 1.f / (1.f + __expf(-fr));
          const float ot = 1.f / (1.f + __expf(-orr));
          const float A = ot * ft;
          const float Bv = ot * (1.f - ft) * zt;
          S = A * S + Bv;
          P = A * P;
        }
      }
    }
  }
  if (tid < 64) {
    const size_t o = ((size_t)bb * NC_ + chunk) * H_ + g * 64 + tid;
    Pws[o] = P;
    Sws[o] = S;
  }
}

// ---------------------------------------------------------------------------
// Kernel 2: compose the 64 chunk-affine maps per (b, h) -> final h_T
// ---------------------------------------------------------------------------
__global__ __launch_bounds__(256) void combine_kernel(const float* __restrict__ Pws,
                                                      const float* __restrict__ Sws,
                                                      float* __restrict__ out) {
  const int idx = blockIdx.x * 256 + threadIdx.x;  // 8192 = B*H
  const int b = idx >> 8;
  const int hh = idx & 255;
  float h = 0.f;
  for (int c = 0; c < NC_; ++c) {
    const float p = Pws[((size_t)b * NC_ + c) * H_ + hh];
    const float s = Sws[((size_t)b * NC_ + c) * H_ + hh];
    h = p * h + s;
  }
  out[idx] = h;
}

// ---------------------------------------------------------------------------
extern "C" void kernel_launch(void* const* d_in, const int* in_sizes, int n_in,
                              void* d_out, int out_size, void* d_ws, size_t ws_size,
                              hipStream_t stream) {
  const float* x = (const float*)d_in[0];
  const float* W = (const float*)d_in[1];
  const float* bias = (const float*)d_in[2];
  float* out = (float*)d_out;

  unsigned short* Wb = (unsigned short*)d_ws;          // 294912 bf16 = 576 KB
  float* Pws = (float*)((char*)d_ws + (1 << 20));      // 2 MB
  float* Sws = Pws + B_ * NC_ * H_;                    // 2 MB

  packW_bf16<<<1152, 256, 0, stream>>>(W, Wb);
  conv_scan_mfma<<<dim3(4, NC_, B_), 256, 0, stream>>>(x, Wb, bias, Pws, Sws);
  combine_kernel<<<32, 256, 0, stream>>>(Pws, Sws, out);
}

// Round 3
// 239.204 us; speedup vs baseline: 5.2633x; 1.3736x over previous
//
#include <hip/hip_runtime.h>
#include <math.h>

// Problem constants
#define B_    32
#define L_    4096
#define CIN_  128
#define H_    256
#define T_    4094          // L - K + 1
#define KTOT_ 384           // CIN * K

#define MT_   128           // timesteps per block (M tile)
#define NTB_  32            // t-blocks (32 * 128 = 4096)
#define NG_   192           // channels per block (z,f,o x 64 h)
#define NKT_  12            // K-steps of 32
#define NCH_  256           // total sub-chunks (NTB_ * 8), 16 steps each
#define GP_   196           // gate LDS pitch in f32 (196*4 % 128B -> 2-way free)

typedef float f32x4 __attribute__((ext_vector_type(4)));
typedef short s16x8 __attribute__((ext_vector_type(8)));

typedef __attribute__((address_space(3))) void lds_void;
typedef const __attribute__((address_space(1))) void gbl_void;

static __device__ __forceinline__ unsigned short f2bf(float f) {
  unsigned u = __builtin_bit_cast(unsigned, f);
  u = (u + 0x7FFFu + ((u >> 16) & 1u)) >> 16;
  return (unsigned short)u;
}

// ---------------------------------------------------------------------------
// Kernel 0: pack W (oc, i, k) fp32 -> bf16 tiles [g][kt][kgrp][c192][kk8]
// (unchanged from round 2 — layout makes linear global_load_lds staging give
// conflict-free MFMA B-fragment reads)
// ---------------------------------------------------------------------------
__global__ __launch_bounds__(256) void packW_bf16(const float* __restrict__ W,
                                                  unsigned short* __restrict__ Wb) {
  const int idx = blockIdx.x * 256 + threadIdx.x;     // 294912 = 1152*256
  const int e = idx & 7;
  int t = idx >> 3;
  const int c = t % NG_;
  t /= NG_;
  const int kgrp = t & 3;
  t >>= 2;
  const int kt = t % NKT_;
  const int g = t / NKT_;
  const int kk = kt * 32 + kgrp * 8 + e;
  const int i = kk & 127, k = kk >> 7;
  const int gate = c >> 6, hl = c & 63;
  const int oc = gate * 256 + g * 64 + hl;
  Wb[idx] = f2bf(W[(size_t)oc * KTOT_ + i * 3 + k]);
}

// ---------------------------------------------------------------------------
// Kernel 1: fused bf16-MFMA conv + activations + wave-parallel fo-pool scan
// grid (1024 = tblk*32+b, 4 h-groups), block 256 (4 waves, 2M x 2N)
// ---------------------------------------------------------------------------
__global__ __launch_bounds__(256, 2) void conv_scan_mfma(
    const float* __restrict__ x, const unsigned short* __restrict__ Wb,
    const float* __restrict__ bias, float* __restrict__ Pws,
    float* __restrict__ Sws) {
  // xs: 130 rows x 128 bf16, 256B pitch, XOR-swizzled        = 33280 B
  // B double-buffer: 2 x 12288 B
  // scan phase aliases smem start: 64 x GP_ f32 gate buffer  = 50176 B
  __shared__ __align__(16) char smem[33280 + 2 * 12288];
  char* xs = smem;
  char* bsh = smem + 33280;
  float* gs = (float*)smem;

  const int tid = threadIdx.x;
  const int w03 = tid >> 6;            // wave 0..3
  const int wm = w03 >> 1;             // M half (rows 64*wm..64*wm+63)
  const int wn = w03 & 1;              // N half (cols 96*wn..96*wn+95)
  const int l = tid & 63;
  const int lr = l & 15;
  const int lg = l >> 4;
  const int tb = blockIdx.x;           // 1024 combos; same tb, diff g = same XCD
  const int g = blockIdx.y;            // h-group 0..3
  const int bb = tb & 31;
  const int tblk = tb >> 5;
  const int t0 = tblk * MT_;

  const unsigned short* wsrc = Wb + (size_t)g * (NKT_ * 6144);

  // ---- prologue: issue B tile kt=0 into half 0 ----
#pragma unroll
  for (int it = 0; it < 3; ++it) {
    __builtin_amdgcn_global_load_lds(
        (gbl_void*)(wsrc + (size_t)(it * 256 + tid) * 8),
        (lds_void*)(bsh + it * 4096 + w03 * 1024), 16, 0, 0);
  }

  // ---- stage x slice (130 rows) fp32 -> bf16 into swizzled xs ----
  for (int v = tid; v < 130 * 32; v += 256) {
    const int row = v >> 5;
    const int colb = (v & 31) * 8;               // byte offset of 4 bf16
    int r = t0 + row;
    if (r > L_ - 1) r = L_ - 1;                  // clamp; feeds only t>=T_, skipped
    const float4 xv = *(const float4*)&x[((size_t)bb * L_ + r) * CIN_ + (v & 31) * 4];
    unsigned p0, p1;
    asm("v_cvt_pk_bf16_f32 %0, %1, %2" : "=v"(p0) : "v"(xv.x), "v"(xv.y));
    asm("v_cvt_pk_bf16_f32 %0, %1, %2" : "=v"(p1) : "v"(xv.z), "v"(xv.w));
    *(uint2*)(xs + row * 256 + (colb ^ ((row & 7) << 4))) = make_uint2(p0, p1);
  }

  // ---- GEMM: M=128 x N=192 x K=384, 12 K-steps, 2-phase pipeline ----
  f32x4 acc[4][6];
#pragma unroll
  for (int mi = 0; mi < 4; ++mi)
#pragma unroll
    for (int nj = 0; nj < 6; ++nj) acc[mi][nj] = (f32x4)0.f;

  for (int kt = 0; kt < NKT_; ++kt) {
    __syncthreads();                             // B[kt] + xs ready
    if (kt < NKT_ - 1) {                         // issue next tile -> other half
      const unsigned short* src = wsrc + (size_t)(kt + 1) * 6144;
      char* dst = bsh + ((kt + 1) & 1) * 12288;
#pragma unroll
      for (int it = 0; it < 3; ++it) {
        __builtin_amdgcn_global_load_lds(
            (gbl_void*)(src + (size_t)(it * 256 + tid) * 8),
            (lds_void*)(dst + it * 4096 + w03 * 1024), 16, 0, 0);
      }
    }
    const int kof = kt >> 2;                     // conv tap 0..2
    const int cb = (kt & 3) * 64 + lg * 16;      // byte col in xs row
    s16x8 a[4], b[6];
#pragma unroll
    for (int mi = 0; mi < 4; ++mi) {
      const int row = wm * 64 + mi * 16 + lr + kof;
      a[mi] = *(const s16x8*)(xs + row * 256 + (cb ^ ((row & 7) << 4)));
    }
    const char* bh = bsh + (kt & 1) * 12288;
#pragma unroll
    for (int nj = 0; nj < 6; ++nj)
      b[nj] = *(const s16x8*)(bh + (lg * NG_ + wn * 96 + nj * 16 + lr) * 16);
#pragma unroll
    for (int mi = 0; mi < 4; ++mi)
#pragma unroll
      for (int nj = 0; nj < 6; ++nj)
        acc[mi][nj] = __builtin_amdgcn_mfma_f32_16x16x32_bf16(a[mi], b[nj], acc[mi][nj], 0, 0, 0);
  }

  // ---- wave-parallel fo-pool scan: 2 passes of 64 rows, 4 sub-chunks each ----
  const float bz = bias[g * 64 + l];
  const float bf = bias[256 + g * 64 + l];
  const float bo = bias[512 + g * 64 + l];

#pragma unroll
  for (int p = 0; p < 2; ++p) {
    __syncthreads();                             // prev readers done (GEMM or pass 0)
    if (wm == p) {                               // waves owning rows [64p,64p+64) write
#pragma unroll
      for (int mi = 0; mi < 4; ++mi)
#pragma unroll
        for (int nj = 0; nj < 6; ++nj)
#pragma unroll
          for (int r = 0; r < 4; ++r) {
            const int rl = mi * 16 + lg * 4 + r; // C frag: col=l&15, row=(l>>4)*4+r
            gs[rl * GP_ + wn * 96 + nj * 16 + lr] = acc[mi][nj][r];
          }
    }
    __syncthreads();
    // wave w03 scans rows [16*w03, 16*w03+16) of this pass
    float P = 1.f, S = 0.f;
#pragma unroll
    for (int mt = 0; mt < 16; ++mt) {
      const int t = t0 + p * 64 + w03 * 16 + mt;
      if (t < T_) {
        const int rl = w03 * 16 + mt;
        const float zr = gs[rl * GP_ + l] + bz;
        const float fr = gs[rl * GP_ + 64 + l] + bf;
        const float orr = gs[rl * GP_ + 128 + l] + bo;
        const float zc = fminf(fmaxf(zr, -15.f), 15.f);
        const float e2 = __expf(2.f * zc);
        const float zt = (e2 - 1.f) * __builtin_amdgcn_rcpf(e2 + 1.f);
        const float ft = __builtin_amdgcn_rcpf(1.f + __expf(-fr));
        const float ot = __builtin_amdgcn_rcpf(1.f + __expf(-orr));
        const float A = ot * ft;
        const float Bv = ot * (1.f - ft) * zt;
        S = A * S + Bv;
        P = A * P;
      }
    }
    const int c = tblk * 8 + p * 4 + w03;        // time-ordered sub-chunk id
    const size_t o = ((size_t)bb * NCH_ + c) * H_ + g * 64 + l;
    Pws[o] = P;
    Sws[o] = S;
  }
}

// ---------------------------------------------------------------------------
// Kernel 2: compose the 256 chunk-affine maps per (b, h) -> final h_T
// ---------------------------------------------------------------------------
__global__ __launch_bounds__(256) void combine_kernel(const float* __restrict__ Pws,
                                                      const float* __restrict__ Sws,
                                                      float* __restrict__ out) {
  const int idx = blockIdx.x * 256 + threadIdx.x;  // 8192 = B*H
  const int b = idx >> 8;
  const int hh = idx & 255;
  float h = 0.f;
  for (int c = 0; c < NCH_; ++c) {
    const float p = Pws[((size_t)b * NCH_ + c) * H_ + hh];
    const float s = Sws[((size_t)b * NCH_ + c) * H_ + hh];
    h = p * h + s;
  }
  out[idx] = h;
}

// ---------------------------------------------------------------------------
extern "C" void kernel_launch(void* const* d_in, const int* in_sizes, int n_in,
                              void* d_out, int out_size, void* d_ws, size_t ws_size,
                              hipStream_t stream) {
  const float* x = (const float*)d_in[0];
  const float* W = (const float*)d_in[1];
  const float* bias = (const float*)d_in[2];
  float* out = (float*)d_out;

  unsigned short* Wb = (unsigned short*)d_ws;          // 576 KB
  float* Pws = (float*)((char*)d_ws + (1 << 20));      // 8 MB
  float* Sws = Pws + (size_t)B_ * NCH_ * H_;           // 8 MB

  packW_bf16<<<1152, 256, 0, stream>>>(W, Wb);
  conv_scan_mfma<<<dim3(1024, 4), 256, 0, stream>>>(x, Wb, bias, Pws, Sws);
  combine_kernel<<<32, 256, 0, stream>>>(Pws, Sws, out);
}

// Round 4
// 207.175 us; speedup vs baseline: 6.0770x; 1.1546x over previous
//
#include <hip/hip_runtime.h>
#include <math.h>

// Problem constants
#define B_    32
#define L_    4096
#define CIN_  128
#define H_    256
#define T_    4094          // L - K + 1
#define KTOT_ 384           // CIN * K

#define MT_   128           // timesteps per block (M tile)
#define NG_   192           // channels per block (z,f,o x 64 h)
#define NKT_  12            // K-steps of 32
#define NCH_  512           // sub-chunks of 8 timesteps (32 tblk * 16)
#define NSEG_ 16            // combine stage-1 segments (32 chunks each)
#define GP_   196           // gate LDS pitch in f32

typedef float f32x4 __attribute__((ext_vector_type(4)));
typedef short s16x8 __attribute__((ext_vector_type(8)));

static __device__ __forceinline__ unsigned short f2bf(float f) {
  unsigned u = __builtin_bit_cast(unsigned, f);
  u = (u + 0x7FFFu + ((u >> 16) & 1u)) >> 16;
  return (unsigned short)u;
}

// ---------------------------------------------------------------------------
// Kernel 0: pack W (oc, i, k) fp32 -> bf16 [g][kt][kgrp][c192][e8]
// Element (g,kt,kgrp,c,e) at idx ((g*12+kt)*4+kgrp)*1536 + c*8 + e.
// B-fragment for (lane lr,lg / wave wn / nj / step kt) is 16 contiguous bytes.
// ---------------------------------------------------------------------------
__global__ __launch_bounds__(256) void packW_bf16(const float* __restrict__ W,
                                                  unsigned short* __restrict__ Wb) {
  const int idx = blockIdx.x * 256 + threadIdx.x;     // 294912 = 1152*256
  const int e = idx & 7;
  int t = idx >> 3;
  const int c = t % NG_;
  t /= NG_;
  const int kgrp = t & 3;
  t >>= 2;
  const int kt = t % NKT_;
  const int g = t / NKT_;
  const int kk = kt * 32 + kgrp * 8 + e;
  const int i = kk & 127, k = kk >> 7;
  const int gate = c >> 6, hl = c & 63;
  const int oc = gate * 256 + g * 64 + hl;
  Wb[idx] = f2bf(W[(size_t)oc * KTOT_ + i * 3 + k]);
}

// ---------------------------------------------------------------------------
// Kernel 1: fused bf16-MFMA conv + activations + wave-parallel fo-pool scan.
// grid (1024 = tblk*32+b, 4 h-groups), block 512 (8 waves = 2M x 4N).
// Barrier-free K-loop: A from LDS (read-only after prologue), B global->VGPR.
// ---------------------------------------------------------------------------
__global__ __launch_bounds__(512, 4) void conv_scan_mfma(
    const float* __restrict__ x, const unsigned short* __restrict__ Wb,
    const float* __restrict__ bias, float* __restrict__ Pws,
    float* __restrict__ Sws) {
  // xs: 130 rows x 128 bf16 (256B pitch, XOR-swizzled) = 33280 B
  // gs (scan phase) overlays the same memory: 64 x GP_ f32 = 50176 B
  __shared__ __align__(16) char smem[64 * GP_ * 4];
  char* xs = smem;
  float* gs = (float*)smem;

  const int tid = threadIdx.x;
  const int w = tid >> 6;              // wave 0..7
  const int wm = w >> 2;               // M half: rows [64*wm, 64*wm+64)
  const int wn = w & 3;                // N quarter: cols [48*wn, 48*wn+48)
  const int l = tid & 63;
  const int lr = l & 15;
  const int lg = l >> 4;
  const int tb = blockIdx.x;
  const int g = blockIdx.y;            // h-group 0..3
  const int bb = tb & 31;
  const int tblk = tb >> 5;
  const int t0 = tblk * MT_;

  // ---- stage x slice (130 rows) fp32 -> bf16 into swizzled xs ----
  for (int v = tid; v < 130 * 32; v += 512) {
    const int row = v >> 5;
    const int colb = (v & 31) * 8;               // byte offset of 4 bf16
    int r = t0 + row;
    if (r > L_ - 1) r = L_ - 1;                  // clamp; feeds only t>=T_, skipped
    const float4 xv = *(const float4*)&x[((size_t)bb * L_ + r) * CIN_ + (v & 31) * 4];
    unsigned p0, p1;
    asm("v_cvt_pk_bf16_f32 %0, %1, %2" : "=v"(p0) : "v"(xv.x), "v"(xv.y));
    asm("v_cvt_pk_bf16_f32 %0, %1, %2" : "=v"(p1) : "v"(xv.z), "v"(xv.w));
    *(uint2*)(xs + row * 256 + (colb ^ ((row & 7) << 4))) = make_uint2(p0, p1);
  }

  // per-lane W base: (g, kt=0, kgrp=lg, c = wn*48 + lr, e=0)
  const unsigned short* bp = Wb + (size_t)g * (NKT_ * 6144) + lg * 1536 + (wn * 48 + lr) * 8;

  f32x4 acc[4][3];
#pragma unroll
  for (int mi = 0; mi < 4; ++mi)
#pragma unroll
    for (int nj = 0; nj < 3; ++nj) acc[mi][nj] = (f32x4)0.f;

  __syncthreads();                               // xs ready; ONLY barrier before scan

  // ---- GEMM: M=128 x N=192 x K=384, fully unrolled, no barriers ----
#pragma unroll
  for (int kt = 0; kt < NKT_; ++kt) {
    const int kof = kt >> 2;                     // conv tap 0..2
    const int cb = (kt & 3) * 64 + lg * 16;      // byte col in xs row
    s16x8 b[3], a[4];
#pragma unroll
    for (int nj = 0; nj < 3; ++nj)
      b[nj] = *(const s16x8*)(bp + kt * 6144 + nj * 128);
#pragma unroll
    for (int mi = 0; mi < 4; ++mi) {
      const int row = wm * 64 + mi * 16 + lr + kof;
      a[mi] = *(const s16x8*)(xs + row * 256 + (cb ^ ((row & 7) << 4)));
    }
#pragma unroll
    for (int mi = 0; mi < 4; ++mi)
#pragma unroll
      for (int nj = 0; nj < 3; ++nj)
        acc[mi][nj] = __builtin_amdgcn_mfma_f32_16x16x32_bf16(a[mi], b[nj], acc[mi][nj], 0, 0, 0);
  }

  // ---- wave-parallel fo-pool scan: 2 passes of 64 rows; 8-step sub-chunks ----
  const float bz = bias[g * 64 + l];
  const float bf = bias[256 + g * 64 + l];
  const float bo = bias[512 + g * 64 + l];

#pragma unroll
  for (int p = 0; p < 2; ++p) {
    __syncthreads();                             // prev readers done (xs dead / pass 0 read)
    if (wm == p) {                               // 4 waves write their 48-col strips
#pragma unroll
      for (int mi = 0; mi < 4; ++mi)
#pragma unroll
        for (int nj = 0; nj < 3; ++nj)
#pragma unroll
          for (int r = 0; r < 4; ++r) {
            const int rl = mi * 16 + lg * 4 + r; // C frag: col=l&15, row=(l>>4)*4+r
            gs[rl * GP_ + wn * 48 + nj * 16 + lr] = acc[mi][nj][r];
          }
    }
    __syncthreads();
    // wave w scans rows [8w, 8w+8) of this pass; all 64 lanes = 64 h channels
    float P = 1.f, S = 0.f;
#pragma unroll
    for (int mt = 0; mt < 8; ++mt) {
      const int t = t0 + p * 64 + w * 8 + mt;
      if (t < T_) {
        const int rl = w * 8 + mt;
        const float zr = gs[rl * GP_ + l] + bz;
        const float fr = gs[rl * GP_ + 64 + l] + bf;
        const float orr = gs[rl * GP_ + 128 + l] + bo;
        const float zc = fminf(fmaxf(zr, -15.f), 15.f);
        const float e2 = __expf(2.f * zc);
        const float zt = (e2 - 1.f) * __builtin_amdgcn_rcpf(e2 + 1.f);
        const float ft = __builtin_amdgcn_rcpf(1.f + __expf(-fr));
        const float ot = __builtin_amdgcn_rcpf(1.f + __expf(-orr));
        const float A = ot * ft;
        const float Bv = ot * (1.f - ft) * zt;
        S = A * S + Bv;
        P = A * P;
      }
    }
    const int c = tblk * 16 + p * 8 + w;         // time-ordered: chunk c covers t=8c..8c+7
    const size_t o = ((size_t)bb * NCH_ + c) * H_ + g * 64 + l;
    Pws[o] = P;
    Sws[o] = S;
  }
}

// ---------------------------------------------------------------------------
// Kernel 2a: compose chunks 32-at-a-time -> 16 segments per (b,h)
// ---------------------------------------------------------------------------
__global__ __launch_bounds__(256) void combine1(const float* __restrict__ Pws,
                                                const float* __restrict__ Sws,
                                                float* __restrict__ P2,
                                                float* __restrict__ S2) {
  const int idx = blockIdx.x * 256 + threadIdx.x; // 131072 = B*NSEG*H
  const int b = idx >> 12;
  const int s = (idx >> 8) & 15;
  const int h = idx & 255;
  float P = 1.f, S = 0.f;
#pragma unroll 4
  for (int c = 0; c < 32; ++c) {
    const size_t o = ((size_t)b * NCH_ + s * 32 + c) * H_ + h;
    const float p = Pws[o];
    const float sv = Sws[o];
    S = p * S + sv;
    P = p * P;
  }
  P2[(b * NSEG_ + s) * H_ + h] = P;
  S2[(b * NSEG_ + s) * H_ + h] = S;
}

// ---------------------------------------------------------------------------
// Kernel 2b: compose the 16 segments -> final h_T
// ---------------------------------------------------------------------------
__global__ __launch_bounds__(256) void combine2(const float* __restrict__ P2,
                                                const float* __restrict__ S2,
                                                float* __restrict__ out) {
  const int idx = blockIdx.x * 256 + threadIdx.x; // 8192 = B*H
  const int b = idx >> 8;
  const int h = idx & 255;
  float hv = 0.f;
#pragma unroll
  for (int s = 0; s < NSEG_; ++s) {
    const float p = P2[(b * NSEG_ + s) * H_ + h];
    const float sv = S2[(b * NSEG_ + s) * H_ + h];
    hv = p * hv + sv;
  }
  out[idx] = hv;
}

// ---------------------------------------------------------------------------
extern "C" void kernel_launch(void* const* d_in, const int* in_sizes, int n_in,
                              void* d_out, int out_size, void* d_ws, size_t ws_size,
                              hipStream_t stream) {
  const float* x = (const float*)d_in[0];
  const float* W = (const float*)d_in[1];
  const float* bias = (const float*)d_in[2];
  float* out = (float*)d_out;

  char* ws = (char*)d_ws;
  unsigned short* Wb = (unsigned short*)ws;                  // 576 KB
  float* Pws = (float*)(ws + (1 << 20));                     // 16 MB
  float* Sws = (float*)(ws + 17 * (1 << 20));                // 16 MB
  float* P2  = (float*)(ws + 33 * (1 << 20));                // 512 KB
  float* S2  = (float*)(ws + 33 * (1 << 20) + (512 << 10));  // 512 KB

  packW_bf16<<<1152, 256, 0, stream>>>(W, Wb);
  conv_scan_mfma<<<dim3(1024, 4), 512, 0, stream>>>(x, Wb, bias, Pws, Sws);
  combine1<<<512, 256, 0, stream>>>(Pws, Sws, P2, S2);
  combine2<<<32, 256, 0, stream>>>(P2, S2, out);
}